// Round 1
// baseline (499.962 us; speedup 1.0000x reference)
//
#include <hip/hip_runtime.h>

typedef unsigned short u16;
typedef unsigned int u32;
typedef __bf16 bf16x8 __attribute__((ext_vector_type(8)));
typedef float f32x4 __attribute__((ext_vector_type(4)));

#define C_DIM 512
#define QKV_N 1536
#define KDIM 512
#define NHEAD 16
#define HD 32
#define H_IMG 128
#define W_IMG 128
#define HW 16384
#define MTOK 16384      // tokens per chunk (one batch image)
#define NWIN_CHUNK 256  // windows per chunk

__device__ __forceinline__ u16 f2bf(float f) {
    u32 u = __builtin_bit_cast(u32, f);
    u += 0x7fffu + ((u >> 16) & 1u);
    return (u16)(u >> 16);
}

// ---------------- prep: weight transpose->bf16, bias matrix ----------------
__global__ void sa_prep_kernel(const float* __restrict__ w_qkv,
                               const float* __restrict__ w_proj,
                               const float* __restrict__ bias_table,
                               u16* __restrict__ wqT, u16* __restrict__ wpT,
                               float* __restrict__ biasP) {
    int t = blockIdx.x * 256 + threadIdx.x;
    const int W1 = KDIM * QKV_N;        // 786432
    const int W2 = KDIM * C_DIM;        // 262144
    const int W3 = NHEAD * 64 * 64;     // 65536
    if (t < W1) {
        int k = t / QKV_N, n = t % QKV_N;
        wqT[n * KDIM + k] = f2bf(w_qkv[t]);
    } else if (t < W1 + W2) {
        int u = t - W1;
        int k = u / C_DIM, n = u % C_DIM;
        wpT[n * KDIM + k] = f2bf(w_proj[u]);
    } else if (t < W1 + W2 + W3) {
        int u = t - W1 - W2;
        int h = u >> 12, n = (u >> 6) & 63, m = u & 63;
        int di = (n >> 3) - (m >> 3) + 7;
        int dj = (n & 7) - (m & 7) + 7;
        biasP[u] = bias_table[(di * 15 + dj) * NHEAD + h];  // [h][n][m]
    }
}

// ---------------- LayerNorm statistics (all 65536 tokens) ----------------
__global__ void sa_ln_stats_kernel(const float* __restrict__ x,
                                   float* __restrict__ mu, float* __restrict__ rsig) {
    int t = blockIdx.x * 256 + threadIdx.x;   // 65536
    int b = t >> 14, s = t & (HW - 1);
    const float* xp = x + (size_t)b * C_DIM * HW + s;
    float sum = 0.f, sq = 0.f;
#pragma unroll 8
    for (int c = 0; c < C_DIM; ++c) {
        float v = xp[(size_t)c * HW];
        sum += v; sq += v * v;
    }
    float m = sum * (1.f / C_DIM);
    float var = sq * (1.f / C_DIM) - m * m;
    mu[t] = m;
    rsig[t] = rsqrtf(var + 1e-5f);
}

// ------------- LN apply + window partition: x(B,C,H,W) -> xn(tok, C) bf16 -------------
__global__ __launch_bounds__(256) void sa_ln_norm_kernel(const float* __restrict__ x,
        const float* __restrict__ gamma, const float* __restrict__ beta,
        const float* __restrict__ mu, const float* __restrict__ rsig,
        u16* __restrict__ xnc, int b) {
    __shared__ float tile[64][129];   // +1 pad: conflict-free transpose
    __shared__ float smu[64], srs[64];
    int win = blockIdx.x >> 2;              // 0..255
    int c0 = (blockIdx.x & 3) * 128;
    int wh = win >> 4, ww = win & 15;
    int tid = threadIdx.x;
    int n = tid & 63;
    int s_base = (wh * 8) * W_IMG + ww * 8;
    if (tid < 64) {
        int s = s_base + (tid >> 3) * W_IMG + (tid & 7);
        smu[tid] = mu[b * HW + s];
        srs[tid] = rsig[b * HW + s];
    }
    int s_n = s_base + (n >> 3) * W_IMG + (n & 7);
    const float* xb = x + (size_t)b * C_DIM * HW;
#pragma unroll
    for (int it = 0; it < 32; ++it) {
        int cl = it * 4 + (tid >> 6);
        tile[n][cl] = xb[(size_t)(c0 + cl) * HW + s_n];
    }
    __syncthreads();
    int cl = tid & 127;
    float g = gamma[c0 + cl], be = beta[c0 + cl];
#pragma unroll
    for (int it = 0; it < 32; ++it) {
        int nn = it * 2 + (tid >> 7);
        float v = (tile[nn][cl] - smu[nn]) * srs[nn] * g + be;
        xnc[(size_t)(win * 64 + nn) * C_DIM + c0 + cl] = f2bf(v);
    }
}

// ---------------- 128x128-tile bf16 GEMM, 4 waves, MFMA 16x16x32 ----------------
// A: (MTOK x 512) bf16 row-major.  BT: (NT x 512) bf16 row-major (B transposed).
// EPI 0: store bf16 to outB (row stride NT).  EPI 1: +bias, un-window scatter fp32.
template <int EPI>
__global__ __launch_bounds__(256) void sa_gemm_kernel(const u16* __restrict__ A,
        const u16* __restrict__ BT, u16* __restrict__ outB, float* __restrict__ outF,
        const float* __restrict__ bias, int nbx, int NT, int bb) {
    __shared__ u16 As[128 * 32];
    __shared__ u16 Bs[128 * 32];
    int mb = blockIdx.x / nbx, nb = blockIdx.x % nbx;
    int m0 = mb * 128, n0 = nb * 128;
    int tid = threadIdx.x;
    int lane = tid & 63, wv = tid >> 6;
    int wr = wv >> 1, wc = wv & 1;
    int lr = lane & 15, lg = lane >> 4;
    f32x4 acc[4][4];
#pragma unroll
    for (int i = 0; i < 4; ++i)
#pragma unroll
        for (int j = 0; j < 4; ++j) acc[i][j] = {0.f, 0.f, 0.f, 0.f};

    for (int kt = 0; kt < KDIM / 32; ++kt) {
        __syncthreads();
#pragma unroll
        for (int p = 0; p < 2; ++p) {
            int idx = p * 256 + tid;
            int row = idx >> 2, seg = idx & 3;
            *reinterpret_cast<uint4*>(&As[row * 32 + seg * 8]) =
                *reinterpret_cast<const uint4*>(&A[(size_t)(m0 + row) * KDIM + kt * 32 + seg * 8]);
            *reinterpret_cast<uint4*>(&Bs[row * 32 + seg * 8]) =
                *reinterpret_cast<const uint4*>(&BT[(size_t)(n0 + row) * KDIM + kt * 32 + seg * 8]);
        }
        __syncthreads();
        bf16x8 af[4], bfr[4];
#pragma unroll
        for (int mt = 0; mt < 4; ++mt)
            af[mt] = *reinterpret_cast<const bf16x8*>(&As[(wr * 64 + mt * 16 + lr) * 32 + lg * 8]);
#pragma unroll
        for (int nt = 0; nt < 4; ++nt)
            bfr[nt] = *reinterpret_cast<const bf16x8*>(&Bs[(wc * 64 + nt * 16 + lr) * 32 + lg * 8]);
#pragma unroll
        for (int mt = 0; mt < 4; ++mt)
#pragma unroll
            for (int nt = 0; nt < 4; ++nt)
                acc[mt][nt] = __builtin_amdgcn_mfma_f32_16x16x32_bf16(af[mt], bfr[nt], acc[mt][nt], 0, 0, 0);
    }

#pragma unroll
    for (int mt = 0; mt < 4; ++mt) {
#pragma unroll
        for (int nt = 0; nt < 4; ++nt) {
            int col = n0 + wc * 64 + nt * 16 + lr;
#pragma unroll
            for (int rr = 0; rr < 4; ++rr) {
                int row = m0 + wr * 64 + mt * 16 + lg * 4 + rr;
                float v = acc[mt][nt][rr];
                if (EPI == 0) {
                    outB[(size_t)row * NT + col] = f2bf(v);
                } else {
                    v += bias[col];
                    int wl = row >> 6, n = row & 63;
                    int h = (wl >> 4) * 8 + (n >> 3);
                    int w = (wl & 15) * 8 + (n & 7);
                    outF[((size_t)(bb * C_DIM + col) * H_IMG + h) * W_IMG + w] = v;
                }
            }
        }
    }
}

// ---------------- attention: one wave per (window, head) ----------------
__global__ __launch_bounds__(64) void sa_attn_kernel(const u16* __restrict__ qkv,
        const float* __restrict__ biasP, u16* __restrict__ attnc) {
    __shared__ u16 VT[32 * 80];   // V transposed [d][n], stride 80 (16B-aligned rows)
    __shared__ u16 Ps[64 * 80];   // P bf16 [n][m], stride 80
    int win = blockIdx.x >> 4, head = blockIdx.x & 15;
    int lane = threadIdx.x, lr = lane & 15, lg = lane >> 4;
    const u16* base = qkv + (size_t)win * 64 * QKV_N + head * HD;

    // stage V transposed into LDS
#pragma unroll
    for (int p = 0; p < 4; ++p) {
        int idx = p * 64 + lane;
        int row = idx >> 2, seg = idx & 3;
        union { uint4 u; u16 s[8]; } cv;
        cv.u = *reinterpret_cast<const uint4*>(base + (size_t)row * QKV_N + 1024 + seg * 8);
#pragma unroll
        for (int e = 0; e < 8; ++e) VT[(seg * 8 + e) * 80 + row] = cv.s[e];
    }

    // Q,K fragments straight from global (A/B frag: row/col = lane&15, k = 8*(lane>>4)+i)
    bf16x8 qa[4], kb[4];
#pragma unroll
    for (int mt = 0; mt < 4; ++mt)
        qa[mt] = *reinterpret_cast<const bf16x8*>(base + (size_t)(mt * 16 + lr) * QKV_N + lg * 8);
#pragma unroll
    for (int nt = 0; nt < 4; ++nt)
        kb[nt] = *reinterpret_cast<const bf16x8*>(base + (size_t)(nt * 16 + lr) * QKV_N + 512 + lg * 8);

    f32x4 sacc[4][4];
#pragma unroll
    for (int i = 0; i < 4; ++i)
#pragma unroll
        for (int j = 0; j < 4; ++j) sacc[i][j] = {0.f, 0.f, 0.f, 0.f};
#pragma unroll
    for (int mt = 0; mt < 4; ++mt)
#pragma unroll
        for (int nt = 0; nt < 4; ++nt)
            sacc[mt][nt] = __builtin_amdgcn_mfma_f32_16x16x32_bf16(qa[mt], kb[nt], sacc[mt][nt], 0, 0, 0);

    __syncthreads();   // VT staged

    // softmax (rows live in 16-lane groups: row = mt*16 + 4*lg + rr, col = nt*16 + lr)
    const float scale = 0.17677669529663687f;  // 32^-0.5
    const float* bp = biasP + head * 64 * 64;
#pragma unroll
    for (int mt = 0; mt < 4; ++mt) {
#pragma unroll
        for (int rr = 0; rr < 4; ++rr) {
            int row = mt * 16 + lg * 4 + rr;
            float vals[4];
#pragma unroll
            for (int nt = 0; nt < 4; ++nt)
                vals[nt] = sacc[mt][nt][rr] * scale + bp[row * 64 + nt * 16 + lr];
            float mx = fmaxf(fmaxf(vals[0], vals[1]), fmaxf(vals[2], vals[3]));
#pragma unroll
            for (int d = 1; d < 16; d <<= 1) mx = fmaxf(mx, __shfl_xor(mx, d, 64));
            float sm = 0.f;
#pragma unroll
            for (int nt = 0; nt < 4; ++nt) { vals[nt] = __expf(vals[nt] - mx); sm += vals[nt]; }
#pragma unroll
            for (int d = 1; d < 16; d <<= 1) sm += __shfl_xor(sm, d, 64);
            float inv = 1.f / sm;
#pragma unroll
            for (int nt = 0; nt < 4; ++nt)
                Ps[row * 80 + nt * 16 + lr] = f2bf(vals[nt] * inv);
        }
    }
    __syncthreads();   // Ps visible

    // O = P @ V  (K=64 -> two k-steps)
    f32x4 oacc[4][2];
#pragma unroll
    for (int i = 0; i < 4; ++i) { oacc[i][0] = {0.f,0.f,0.f,0.f}; oacc[i][1] = {0.f,0.f,0.f,0.f}; }
#pragma unroll
    for (int ks = 0; ks < 2; ++ks) {
        bf16x8 pa[4], vb[2];
#pragma unroll
        for (int mt = 0; mt < 4; ++mt)
            pa[mt] = *reinterpret_cast<const bf16x8*>(&Ps[(mt * 16 + lr) * 80 + ks * 32 + lg * 8]);
#pragma unroll
        for (int n2 = 0; n2 < 2; ++n2)
            vb[n2] = *reinterpret_cast<const bf16x8*>(&VT[(n2 * 16 + lr) * 80 + ks * 32 + lg * 8]);
#pragma unroll
        for (int mt = 0; mt < 4; ++mt)
#pragma unroll
            for (int n2 = 0; n2 < 2; ++n2)
                oacc[mt][n2] = __builtin_amdgcn_mfma_f32_16x16x32_bf16(pa[mt], vb[n2], oacc[mt][n2], 0, 0, 0);
    }

#pragma unroll
    for (int mt = 0; mt < 4; ++mt)
#pragma unroll
        for (int n2 = 0; n2 < 2; ++n2)
#pragma unroll
            for (int rr = 0; rr < 4; ++rr) {
                int row = mt * 16 + lg * 4 + rr;
                attnc[(size_t)(win * 64 + row) * C_DIM + head * HD + n2 * 16 + lr] =
                    f2bf(oacc[mt][n2][rr]);
            }
}

// ---------------- host ----------------
extern "C" void kernel_launch(void* const* d_in, const int* in_sizes, int n_in,
                              void* d_out, int out_size, void* d_ws, size_t ws_size,
                              hipStream_t stream) {
    const float* x          = (const float*)d_in[0];
    const float* gamma      = (const float*)d_in[1];
    const float* beta       = (const float*)d_in[2];
    const float* w_qkv      = (const float*)d_in[3];
    const float* w_proj     = (const float*)d_in[4];
    const float* b_proj     = (const float*)d_in[5];
    const float* bias_table = (const float*)d_in[6];
    float* out = (float*)d_out;

    char* ws = (char*)d_ws;
    size_t off = 0;
    auto alloc = [&](size_t bytes) {
        char* p = ws + off;
        off += (bytes + 255) & ~(size_t)255;
        return p;
    };
    u16*   wqT   = (u16*)alloc((size_t)KDIM * QKV_N * 2);       // 1.5 MB
    u16*   wpT   = (u16*)alloc((size_t)KDIM * C_DIM * 2);       // 0.5 MB
    float* biasP = (float*)alloc((size_t)NHEAD * 64 * 64 * 4);  // 256 KB
    float* mu    = (float*)alloc((size_t)4 * HW * 4);           // 256 KB
    float* rsig  = (float*)alloc((size_t)4 * HW * 4);           // 256 KB
    u16*   xnc   = (u16*)alloc((size_t)MTOK * C_DIM * 2);       // 16 MB
    u16*   qkvc  = (u16*)alloc((size_t)MTOK * QKV_N * 2);       // 48 MB
    u16*   attnc = (u16*)alloc((size_t)MTOK * C_DIM * 2);       // 16 MB

    sa_prep_kernel<<<4352, 256, 0, stream>>>(w_qkv, w_proj, bias_table, wqT, wpT, biasP);
    sa_ln_stats_kernel<<<256, 256, 0, stream>>>(x, mu, rsig);

    for (int b = 0; b < 4; ++b) {
        sa_ln_norm_kernel<<<1024, 256, 0, stream>>>(x, gamma, beta, mu, rsig, xnc, b);
        sa_gemm_kernel<0><<<128 * 12, 256, 0, stream>>>(xnc, wqT, qkvc, nullptr, nullptr, 12, QKV_N, 0);
        sa_attn_kernel<<<NWIN_CHUNK * NHEAD, 64, 0, stream>>>(qkvc, biasP, attnc);
        sa_gemm_kernel<1><<<128 * 4, 256, 0, stream>>>(attnc, wpT, nullptr, out, b_proj, 4, C_DIM, b);
    }
}

// Round 2
// 432.566 us; speedup vs baseline: 1.1558x; 1.1558x over previous
//
#include <hip/hip_runtime.h>

typedef unsigned short u16;
typedef unsigned int u32;
typedef __bf16 bf16x8 __attribute__((ext_vector_type(8)));
typedef float f32x4 __attribute__((ext_vector_type(4)));

#define C_DIM 512
#define QKV_N 1536
#define KDIM 512
#define NHEAD 16
#define HD 32
#define H_IMG 128
#define W_IMG 128
#define HW 16384
#define NTOK 65536      // all tokens, 4 batch images
#define NWIN 1024

#define GLL(g, l) __builtin_amdgcn_global_load_lds( \
    (const __attribute__((address_space(1))) u32*)(g), \
    (__attribute__((address_space(3))) u32*)(l), 16, 0, 0)

__device__ __forceinline__ u16 f2bf(float f) {
    u32 u = __builtin_bit_cast(u32, f);
    u += 0x7fffu + ((u >> 16) & 1u);
    return (u16)(u >> 16);
}

// ---------------- prep: weight transpose->bf16, bias matrix ----------------
__global__ void sa_prep_kernel(const float* __restrict__ w_qkv,
                               const float* __restrict__ w_proj,
                               const float* __restrict__ bias_table,
                               u16* __restrict__ wqT, u16* __restrict__ wpT,
                               float* __restrict__ biasP) {
    int t = blockIdx.x * 256 + threadIdx.x;
    const int W1 = KDIM * QKV_N;        // 786432
    const int W2 = KDIM * C_DIM;        // 262144
    const int W3 = NHEAD * 64 * 64;     // 65536
    if (t < W1) {
        int k = t / QKV_N, n = t % QKV_N;
        wqT[n * KDIM + k] = f2bf(w_qkv[t]);
    } else if (t < W1 + W2) {
        int u = t - W1;
        int k = u / C_DIM, n = u % C_DIM;
        wpT[n * KDIM + k] = f2bf(w_proj[u]);
    } else if (t < W1 + W2 + W3) {
        int u = t - W1 - W2;
        int h = u >> 12, n = (u >> 6) & 63, m = u & 63;
        int di = (n >> 3) - (m >> 3) + 7;
        int dj = (n & 7) - (m & 7) + 7;
        biasP[u] = bias_table[(di * 15 + dj) * NHEAD + h];  // [h][n][m]
    }
}

// ---------------- LayerNorm statistics: 64 token-quads x 4 c-quarters per block ----------------
__global__ __launch_bounds__(256) void sa_ln_stats_kernel(const float* __restrict__ x,
                                   float* __restrict__ mu, float* __restrict__ rsig) {
    __shared__ float ssum[4][64][4];
    __shared__ float ssq[4][64][4];
    int q  = threadIdx.x & 63;
    int cq = threadIdx.x >> 6;
    int quad = blockIdx.x * 64 + q;       // 0..16383
    int tok4 = quad * 4;
    int b = tok4 >> 14, s = tok4 & (HW - 1);
    const float* xp = x + (size_t)b * C_DIM * HW + (size_t)cq * 128 * HW + s;
    float sx = 0.f, sy = 0.f, sz = 0.f, sw = 0.f;
    float qx = 0.f, qy = 0.f, qz = 0.f, qw = 0.f;
#pragma unroll 4
    for (int c = 0; c < 128; ++c) {
        float4 v = *reinterpret_cast<const float4*>(xp + (size_t)c * HW);
        sx += v.x; sy += v.y; sz += v.z; sw += v.w;
        qx += v.x * v.x; qy += v.y * v.y; qz += v.z * v.z; qw += v.w * v.w;
    }
    ssum[cq][q][0] = sx; ssum[cq][q][1] = sy; ssum[cq][q][2] = sz; ssum[cq][q][3] = sw;
    ssq[cq][q][0] = qx;  ssq[cq][q][1] = qy;  ssq[cq][q][2] = qz;  ssq[cq][q][3] = qw;
    __syncthreads();
    if (threadIdx.x < 64) {
#pragma unroll
        for (int j = 0; j < 4; ++j) {
            float S = ssum[0][q][j] + ssum[1][q][j] + ssum[2][q][j] + ssum[3][q][j];
            float Q = ssq[0][q][j] + ssq[1][q][j] + ssq[2][q][j] + ssq[3][q][j];
            float m = S * (1.f / C_DIM);
            float var = Q * (1.f / C_DIM) - m * m;
            mu[tok4 + j] = m;
            rsig[tok4 + j] = rsqrtf(var + 1e-5f);
        }
    }
}

// ------------- LN apply + window partition: x(B,C,H,W) -> xn(tok, C) bf16 -------------
__global__ __launch_bounds__(256) void sa_ln_norm_kernel(const float* __restrict__ x,
        const float* __restrict__ gamma, const float* __restrict__ beta,
        const float* __restrict__ mu, const float* __restrict__ rsig,
        u16* __restrict__ xnc) {
    __shared__ float tile[64][129];   // +1 pad: conflict-free transpose
    __shared__ float smu[64], srs[64];
    int b = blockIdx.x >> 10;
    int r = blockIdx.x & 1023;
    int win = r >> 2;                       // 0..255
    int c0 = (r & 3) * 128;
    int wh = win >> 4, ww = win & 15;
    int tid = threadIdx.x;
    int n = tid & 63;
    int s_base = (wh * 8) * W_IMG + ww * 8;
    if (tid < 64) {
        int s = s_base + (tid >> 3) * W_IMG + (tid & 7);
        smu[tid] = mu[b * HW + s];
        srs[tid] = rsig[b * HW + s];
    }
    int s_n = s_base + (n >> 3) * W_IMG + (n & 7);
    const float* xb = x + (size_t)b * C_DIM * HW;
#pragma unroll
    for (int it = 0; it < 32; ++it) {
        int cl = it * 4 + (tid >> 6);
        tile[n][cl] = xb[(size_t)(c0 + cl) * HW + s_n];
    }
    __syncthreads();
    int cl = tid & 127;
    float g = gamma[c0 + cl], be = beta[c0 + cl];
#pragma unroll
    for (int it = 0; it < 32; ++it) {
        int nn = it * 2 + (tid >> 7);
        float v = (tile[nn][cl] - smu[nn]) * srs[nn] * g + be;
        xnc[(size_t)(((b << 8) + win) * 64 + nn) * C_DIM + c0 + cl] = f2bf(v);
    }
}

// ---------------- 128x128-tile bf16 GEMM, global_load_lds staging (m97 structure) ----------------
// A: (M x 512) bf16 row-major.  BT: (NT x 512) bf16 row-major (B transposed).
// EPI 0: store bf16 to outB (row stride NT).  EPI 1: +bias, un-window scatter fp32 (float4).
template <int EPI>
__global__ __launch_bounds__(256) void sa_gemm_kernel(const u16* __restrict__ A,
        const u16* __restrict__ BT, u16* __restrict__ outB, float* __restrict__ outF,
        const float* __restrict__ bias, int nbx, int NT) {
    __shared__ u16 As[128 * 32];
    __shared__ u16 Bs[128 * 32];
    const int tid = threadIdx.x;
    const int mb = blockIdx.x / nbx, nb = blockIdx.x % nbx;
    const int m0 = mb * 128, n0 = nb * 128;
    const int lane = tid & 63, wv = tid >> 6;
    const int wr = wv >> 1, wc = wv & 1;
    const int lr = lane & 15, lg = lane >> 4;

    // staging: idx = wv*64+lane = tid covers rows 0..63 (instr 0), +256 covers rows 64..127
    const u16* Ag = A  + (size_t)(m0 + (tid >> 2)) * KDIM + (tid & 3) * 8;
    const u16* Bg = BT + (size_t)(n0 + (tid >> 2)) * KDIM + (tid & 3) * 8;
    u16* AsW = As + wv * 512;   // wave-uniform LDS base (bytes: wv*1024)
    u16* BsW = Bs + wv * 512;
    const size_t rstep = (size_t)64 * KDIM;

    f32x4 acc[4][4];
#pragma unroll
    for (int i = 0; i < 4; ++i)
#pragma unroll
        for (int j = 0; j < 4; ++j) acc[i][j] = {0.f, 0.f, 0.f, 0.f};

    for (int kt = 0; kt < KDIM / 32; ++kt) {
        __syncthreads();                       // prior ds_reads done before overwrite
        GLL(Ag + kt * 32,         AsW);
        GLL(Ag + kt * 32 + rstep, AsW + 2048);
        GLL(Bg + kt * 32,         BsW);
        GLL(Bg + kt * 32 + rstep, BsW + 2048);
        __syncthreads();                       // vmcnt(0) drained by compiler before barrier
        bf16x8 af[4], bfr[4];
#pragma unroll
        for (int mt = 0; mt < 4; ++mt)
            af[mt] = *reinterpret_cast<const bf16x8*>(&As[(wr * 64 + mt * 16 + lr) * 32 + lg * 8]);
#pragma unroll
        for (int nt = 0; nt < 4; ++nt)
            bfr[nt] = *reinterpret_cast<const bf16x8*>(&Bs[(wc * 64 + nt * 16 + lr) * 32 + lg * 8]);
#pragma unroll
        for (int mt = 0; mt < 4; ++mt)
#pragma unroll
            for (int nt = 0; nt < 4; ++nt)
                acc[mt][nt] = __builtin_amdgcn_mfma_f32_16x16x32_bf16(af[mt], bfr[nt], acc[mt][nt], 0, 0, 0);
    }

    if (EPI == 0) {
#pragma unroll
        for (int mt = 0; mt < 4; ++mt) {
#pragma unroll
            for (int nt = 0; nt < 4; ++nt) {
                int col = n0 + wc * 64 + nt * 16 + lr;
#pragma unroll
                for (int rr = 0; rr < 4; ++rr) {
                    int row = m0 + wr * 64 + mt * 16 + lg * 4 + rr;
                    outB[(size_t)row * NT + col] = f2bf(acc[mt][nt][rr]);
                }
            }
        }
    } else {
#pragma unroll
        for (int mt = 0; mt < 4; ++mt) {
            int rowb = m0 + wr * 64 + mt * 16 + lg * 4;   // rows rowb..rowb+3 = 4 consecutive w
            int win = rowb >> 6, n = rowb & 63;
            int b = win >> 8, wl = win & 255;
            int h = ((wl >> 4) << 3) + (n >> 3);
            int w = ((wl & 15) << 3) + (n & 7);
            float* op = outF + (size_t)b * C_DIM * HW + (size_t)h * W_IMG + w;
#pragma unroll
            for (int nt = 0; nt < 4; ++nt) {
                int col = n0 + wc * 64 + nt * 16 + lr;
                float bb = bias[col];
                float4 v;
                v.x = acc[mt][nt][0] + bb;
                v.y = acc[mt][nt][1] + bb;
                v.z = acc[mt][nt][2] + bb;
                v.w = acc[mt][nt][3] + bb;
                *reinterpret_cast<float4*>(op + (size_t)col * HW) = v;
            }
        }
    }
}

// ---------------- attention: one wave per (window, head) ----------------
__global__ __launch_bounds__(64) void sa_attn_kernel(const u16* __restrict__ qkv,
        const float* __restrict__ biasP, u16* __restrict__ attnc) {
    __shared__ u16 VT[32 * 80];   // V transposed [d][n], stride 80 (16B-aligned rows)
    __shared__ u16 Ps[64 * 80];   // P bf16 [n][m], stride 80
    int win = blockIdx.x >> 4, head = blockIdx.x & 15;
    int lane = threadIdx.x, lr = lane & 15, lg = lane >> 4;
    const u16* base = qkv + (size_t)win * 64 * QKV_N + head * HD;

    // stage V transposed into LDS
#pragma unroll
    for (int p = 0; p < 4; ++p) {
        int idx = p * 64 + lane;
        int row = idx >> 2, seg = idx & 3;
        union { uint4 u; u16 s[8]; } cv;
        cv.u = *reinterpret_cast<const uint4*>(base + (size_t)row * QKV_N + 1024 + seg * 8);
#pragma unroll
        for (int e = 0; e < 8; ++e) VT[(seg * 8 + e) * 80 + row] = cv.s[e];
    }

    // Q,K fragments straight from global (A/B frag: row/col = lane&15, k = 8*(lane>>4)+i)
    bf16x8 qa[4], kb[4];
#pragma unroll
    for (int mt = 0; mt < 4; ++mt)
        qa[mt] = *reinterpret_cast<const bf16x8*>(base + (size_t)(mt * 16 + lr) * QKV_N + lg * 8);
#pragma unroll
    for (int nt = 0; nt < 4; ++nt)
        kb[nt] = *reinterpret_cast<const bf16x8*>(base + (size_t)(nt * 16 + lr) * QKV_N + 512 + lg * 8);

    f32x4 sacc[4][4];
#pragma unroll
    for (int i = 0; i < 4; ++i)
#pragma unroll
        for (int j = 0; j < 4; ++j) sacc[i][j] = {0.f, 0.f, 0.f, 0.f};
#pragma unroll
    for (int mt = 0; mt < 4; ++mt)
#pragma unroll
        for (int nt = 0; nt < 4; ++nt)
            sacc[mt][nt] = __builtin_amdgcn_mfma_f32_16x16x32_bf16(qa[mt], kb[nt], sacc[mt][nt], 0, 0, 0);

    __syncthreads();   // VT staged

    // softmax (rows live in 16-lane groups: row = mt*16 + 4*lg + rr, col = nt*16 + lr)
    const float scale = 0.17677669529663687f;  // 32^-0.5
    const float* bp = biasP + head * 64 * 64;
#pragma unroll
    for (int mt = 0; mt < 4; ++mt) {
#pragma unroll
        for (int rr = 0; rr < 4; ++rr) {
            int row = mt * 16 + lg * 4 + rr;
            float vals[4];
#pragma unroll
            for (int nt = 0; nt < 4; ++nt)
                vals[nt] = sacc[mt][nt][rr] * scale + bp[row * 64 + nt * 16 + lr];
            float mx = fmaxf(fmaxf(vals[0], vals[1]), fmaxf(vals[2], vals[3]));
#pragma unroll
            for (int d = 1; d < 16; d <<= 1) mx = fmaxf(mx, __shfl_xor(mx, d, 64));
            float sm = 0.f;
#pragma unroll
            for (int nt = 0; nt < 4; ++nt) { vals[nt] = __expf(vals[nt] - mx); sm += vals[nt]; }
#pragma unroll
            for (int d = 1; d < 16; d <<= 1) sm += __shfl_xor(sm, d, 64);
            float inv = 1.f / sm;
#pragma unroll
            for (int nt = 0; nt < 4; ++nt)
                Ps[row * 80 + nt * 16 + lr] = f2bf(vals[nt] * inv);
        }
    }
    __syncthreads();   // Ps visible

    // O = P @ V  (K=64 -> two k-steps)
    f32x4 oacc[4][2];
#pragma unroll
    for (int i = 0; i < 4; ++i) { oacc[i][0] = {0.f,0.f,0.f,0.f}; oacc[i][1] = {0.f,0.f,0.f,0.f}; }
#pragma unroll
    for (int ks = 0; ks < 2; ++ks) {
        bf16x8 pa[4], vb[2];
#pragma unroll
        for (int mt = 0; mt < 4; ++mt)
            pa[mt] = *reinterpret_cast<const bf16x8*>(&Ps[(mt * 16 + lr) * 80 + ks * 32 + lg * 8]);
#pragma unroll
        for (int n2 = 0; n2 < 2; ++n2)
            vb[n2] = *reinterpret_cast<const bf16x8*>(&VT[(n2 * 16 + lr) * 80 + ks * 32 + lg * 8]);
#pragma unroll
        for (int mt = 0; mt < 4; ++mt)
#pragma unroll
            for (int n2 = 0; n2 < 2; ++n2)
                oacc[mt][n2] = __builtin_amdgcn_mfma_f32_16x16x32_bf16(pa[mt], vb[n2], oacc[mt][n2], 0, 0, 0);
    }

#pragma unroll
    for (int mt = 0; mt < 4; ++mt)
#pragma unroll
        for (int n2 = 0; n2 < 2; ++n2)
#pragma unroll
            for (int rr = 0; rr < 4; ++rr) {
                int row = mt * 16 + lg * 4 + rr;
                attnc[(size_t)(win * 64 + row) * C_DIM + head * HD + n2 * 16 + lr] =
                    f2bf(oacc[mt][n2][rr]);
            }
}

// ---------------- host ----------------
extern "C" void kernel_launch(void* const* d_in, const int* in_sizes, int n_in,
                              void* d_out, int out_size, void* d_ws, size_t ws_size,
                              hipStream_t stream) {
    const float* x          = (const float*)d_in[0];
    const float* gamma      = (const float*)d_in[1];
    const float* beta       = (const float*)d_in[2];
    const float* w_qkv      = (const float*)d_in[3];
    const float* w_proj     = (const float*)d_in[4];
    const float* b_proj     = (const float*)d_in[5];
    const float* bias_table = (const float*)d_in[6];
    float* out = (float*)d_out;

    char* ws = (char*)d_ws;
    size_t off = 0;
    auto alloc = [&](size_t bytes) {
        char* p = ws + off;
        off += (bytes + 255) & ~(size_t)255;
        return p;
    };
    u16*   wqT   = (u16*)alloc((size_t)KDIM * QKV_N * 2);       // 1.5 MB
    u16*   wpT   = (u16*)alloc((size_t)KDIM * C_DIM * 2);       // 0.5 MB
    float* biasP = (float*)alloc((size_t)NHEAD * 64 * 64 * 4);  // 256 KB
    float* mu    = (float*)alloc((size_t)NTOK * 4);             // 256 KB
    float* rsig  = (float*)alloc((size_t)NTOK * 4);             // 256 KB
    u16*   xnc   = (u16*)alloc((size_t)NTOK * C_DIM * 2);       // 64 MB
    u16*   qkvc  = (u16*)alloc((size_t)NTOK * QKV_N * 2);       // 192 MB
    u16*   attnc = (u16*)alloc((size_t)NTOK * C_DIM * 2);       // 64 MB

    sa_prep_kernel<<<4352, 256, 0, stream>>>(w_qkv, w_proj, bias_table, wqT, wpT, biasP);
    sa_ln_stats_kernel<<<256, 256, 0, stream>>>(x, mu, rsig);
    sa_ln_norm_kernel<<<4096, 256, 0, stream>>>(x, gamma, beta, mu, rsig, xnc);
    sa_gemm_kernel<0><<<512 * 12, 256, 0, stream>>>(xnc, wqT, qkvc, nullptr, nullptr, 12, QKV_N);
    sa_attn_kernel<<<NWIN * NHEAD, 64, 0, stream>>>(qkvc, biasP, attnc);
    sa_gemm_kernel<1><<<512 * 4, 256, 0, stream>>>(attnc, wpT, nullptr, out, b_proj, 4, C_DIM);
}

// Round 3
// 377.821 us; speedup vs baseline: 1.3233x; 1.1449x over previous
//
#include <hip/hip_runtime.h>

typedef unsigned short u16;
typedef unsigned int u32;
typedef __bf16 bf16x8 __attribute__((ext_vector_type(8)));
typedef float f32x4 __attribute__((ext_vector_type(4)));

#define C_DIM 512
#define QKV_N 1536
#define KDIM 512
#define NHEAD 16
#define HD 32
#define H_IMG 128
#define W_IMG 128
#define HW 16384
#define NTOK 65536
#define NWIN 1024

#define GLL(g, l) __builtin_amdgcn_global_load_lds( \
    (const __attribute__((address_space(1))) u32*)(g), \
    (__attribute__((address_space(3))) u32*)(l), 16, 0, 0)

#define BAR() __builtin_amdgcn_s_barrier()
#define LGKM0() asm volatile("s_waitcnt lgkmcnt(0)" ::: "memory")
#define VM6() asm volatile("s_waitcnt vmcnt(6)" ::: "memory")
#define VM4() asm volatile("s_waitcnt vmcnt(4)" ::: "memory")
#define VM0() asm volatile("s_waitcnt vmcnt(0)" ::: "memory")

__device__ __forceinline__ u16 f2bf(float f) {
    u32 u = __builtin_bit_cast(u32, f);
    u += 0x7fffu + ((u >> 16) & 1u);
    return (u16)(u >> 16);
}

// ---------------- prep: weight transpose->bf16, bias matrix ----------------
__global__ void sa_prep_kernel(const float* __restrict__ w_qkv,
                               const float* __restrict__ w_proj,
                               const float* __restrict__ bias_table,
                               u16* __restrict__ wqT, u16* __restrict__ wpT,
                               float* __restrict__ biasP) {
    int t = blockIdx.x * 256 + threadIdx.x;
    const int W1 = KDIM * QKV_N;
    const int W2 = KDIM * C_DIM;
    const int W3 = NHEAD * 64 * 64;
    if (t < W1) {
        int k = t / QKV_N, n = t % QKV_N;
        wqT[n * KDIM + k] = f2bf(w_qkv[t]);
    } else if (t < W1 + W2) {
        int u = t - W1;
        int k = u / C_DIM, n = u % C_DIM;
        wpT[n * KDIM + k] = f2bf(w_proj[u]);
    } else if (t < W1 + W2 + W3) {
        int u = t - W1 - W2;
        int h = u >> 12, n = (u >> 6) & 63, m = u & 63;
        int di = (n >> 3) - (m >> 3) + 7;
        int dj = (n & 7) - (m & 7) + 7;
        biasP[u] = bias_table[(di * 15 + dj) * NHEAD + h];
    }
}

// ---------------- LayerNorm statistics ----------------
__global__ __launch_bounds__(256) void sa_ln_stats_kernel(const float* __restrict__ x,
                                   float* __restrict__ mu, float* __restrict__ rsig) {
    __shared__ float ssum[4][64][4];
    __shared__ float ssq[4][64][4];
    int q  = threadIdx.x & 63;
    int cq = threadIdx.x >> 6;
    int quad = blockIdx.x * 64 + q;
    int tok4 = quad * 4;
    int b = tok4 >> 14, s = tok4 & (HW - 1);
    const float* xp = x + (size_t)b * C_DIM * HW + (size_t)cq * 128 * HW + s;
    float sx = 0.f, sy = 0.f, sz = 0.f, sw = 0.f;
    float qx = 0.f, qy = 0.f, qz = 0.f, qw = 0.f;
#pragma unroll 4
    for (int c = 0; c < 128; ++c) {
        float4 v = *reinterpret_cast<const float4*>(xp + (size_t)c * HW);
        sx += v.x; sy += v.y; sz += v.z; sw += v.w;
        qx += v.x * v.x; qy += v.y * v.y; qz += v.z * v.z; qw += v.w * v.w;
    }
    ssum[cq][q][0] = sx; ssum[cq][q][1] = sy; ssum[cq][q][2] = sz; ssum[cq][q][3] = sw;
    ssq[cq][q][0] = qx;  ssq[cq][q][1] = qy;  ssq[cq][q][2] = qz;  ssq[cq][q][3] = qw;
    __syncthreads();
    if (threadIdx.x < 64) {
#pragma unroll
        for (int j = 0; j < 4; ++j) {
            float S = ssum[0][q][j] + ssum[1][q][j] + ssum[2][q][j] + ssum[3][q][j];
            float Q = ssq[0][q][j] + ssq[1][q][j] + ssq[2][q][j] + ssq[3][q][j];
            float m = S * (1.f / C_DIM);
            float var = Q * (1.f / C_DIM) - m * m;
            mu[tok4 + j] = m;
            rsig[tok4 + j] = rsqrtf(var + 1e-5f);
        }
    }
}

// ------------- LN apply + window partition -------------
__global__ __launch_bounds__(256) void sa_ln_norm_kernel(const float* __restrict__ x,
        const float* __restrict__ gamma, const float* __restrict__ beta,
        const float* __restrict__ mu, const float* __restrict__ rsig,
        u16* __restrict__ xnc) {
    __shared__ float tile[64][129];
    __shared__ float smu[64], srs[64];
    int b = blockIdx.x >> 10;
    int r = blockIdx.x & 1023;
    int win = r >> 2;
    int c0 = (r & 3) * 128;
    int wh = win >> 4, ww = win & 15;
    int tid = threadIdx.x;
    int n = tid & 63;
    int s_base = (wh * 8) * W_IMG + ww * 8;
    if (tid < 64) {
        int s = s_base + (tid >> 3) * W_IMG + (tid & 7);
        smu[tid] = mu[b * HW + s];
        srs[tid] = rsig[b * HW + s];
    }
    int s_n = s_base + (n >> 3) * W_IMG + (n & 7);
    const float* xb = x + (size_t)b * C_DIM * HW;
#pragma unroll
    for (int it = 0; it < 32; ++it) {
        int cl = it * 4 + (tid >> 6);
        tile[n][cl] = xb[(size_t)(c0 + cl) * HW + s_n];
    }
    __syncthreads();
    int cl = tid & 127;
    float g = gamma[c0 + cl], be = beta[c0 + cl];
#pragma unroll
    for (int it = 0; it < 32; ++it) {
        int nn = it * 2 + (tid >> 7);
        float v = (tile[nn][cl] - smu[nn]) * srs[nn] * g + be;
        xnc[(size_t)(((b << 8) + win) * 64 + nn) * C_DIM + c0 + cl] = f2bf(v);
    }
}

// ============ 256x256-tile BK=64 8-phase bf16 GEMM (m201-style template) ============
// A: (M x 512) bf16 row-major. BT: (NT x 512) bf16 row-major.
// EPI 0: bf16 out, row stride NT.  EPI 1: +bias, un-window scatter fp32 via LDS transpose.
// LDS swizzle: logical kslot stored at phys = kslot ^ ((row&3)<<1); GLL source pre-swizzled.

#define LDA1(Q,J,KK,BUF) af[Q][J][KK] = *reinterpret_cast<const bf16x8*>( \
    &lds[(BUF)*16384 + (wr*128 + ((Q)*2+(J))*16 + lr)*64 + ((((KK)*4)+lg) ^ ((lr&3)<<1))*8])
#define LDAQ(Q,BUF) do{ LDA1(Q,0,0,BUF); LDA1(Q,0,1,BUF); LDA1(Q,1,0,BUF); LDA1(Q,1,1,BUF); }while(0)
#define LDB1(NF,KK,BUF) bfr[NF][KK] = *reinterpret_cast<const bf16x8*>( \
    &lds[32768 + (BUF)*16384 + (wc*64 + (NF)*16 + lr)*64 + ((((KK)*4)+lg) ^ ((lr&3)<<1))*8])
#define LDB(BUF) do{ LDB1(0,0,BUF); LDB1(0,1,BUF); LDB1(1,0,BUF); LDB1(1,1,BUF); \
                     LDB1(2,0,BUF); LDB1(2,1,BUF); LDB1(3,0,BUF); LDB1(3,1,BUF); }while(0)
#define MFMA1(M,N,KK) acc[M][N] = __builtin_amdgcn_mfma_f32_16x16x32_bf16(af[(M)/2][(M)&1][KK], bfr[N][KK], acc[M][N], 0, 0, 0)
#define MFMAQ(Q) do{ __builtin_amdgcn_s_setprio(1); \
    MFMA1(2*(Q),0,0);   MFMA1(2*(Q),0,1);   MFMA1(2*(Q),1,0);   MFMA1(2*(Q),1,1); \
    MFMA1(2*(Q),2,0);   MFMA1(2*(Q),2,1);   MFMA1(2*(Q),3,0);   MFMA1(2*(Q),3,1); \
    MFMA1(2*(Q)+1,0,0); MFMA1(2*(Q)+1,0,1); MFMA1(2*(Q)+1,1,0); MFMA1(2*(Q)+1,1,1); \
    MFMA1(2*(Q)+1,2,0); MFMA1(2*(Q)+1,2,1); MFMA1(2*(Q)+1,3,0); MFMA1(2*(Q)+1,3,1); \
    __builtin_amdgcn_s_setprio(0); }while(0)
#define STAGE_A(KT, H) do{ const u16* _s = Asrc + (KT)*64 + (size_t)((H)*128)*KDIM; \
    u16* _d = Adst + ((KT)&1)*16384 + (H)*8192; \
    GLL(_s, _d); GLL(_s + (size_t)64*KDIM, _d + 4096); }while(0)
#define STAGE_B(KT, H) do{ const u16* _s = Bsrc + (KT)*64 + (size_t)((H)*128)*KDIM; \
    u16* _d = Bdst + ((KT)&1)*16384 + (H)*8192; \
    GLL(_s, _d); GLL(_s + (size_t)64*KDIM, _d + 4096); }while(0)

template <int EPI>
__global__ __launch_bounds__(512, 2) void sa_gemm8_kernel(const u16* __restrict__ A,
        const u16* __restrict__ BT, u16* __restrict__ outB, float* __restrict__ outF,
        const float* __restrict__ bias, int nbx, int NT) {
    __shared__ u16 lds[65536];   // 128 KB: A[2][256][64] | B[2][256][64]

    const int tid = threadIdx.x;
    // XCD-aware bijective swizzle (grid % 8 == 0 for both call sites)
    const int cpx = gridDim.x >> 3;
    const int wg = (blockIdx.x & 7) * cpx + (blockIdx.x >> 3);
    const int mb = wg / nbx, nb = wg % nbx;
    const int m0 = mb * 256, n0 = nb * 256;
    const int lane = tid & 63, wv = tid >> 6;
    const int wr = wv >> 2, wc = wv & 3;         // 2M x 4N waves
    const int lr = lane & 15, lg = lane >> 4;

    // staging source (pre-swizzled so linear LDS dest + swizzled read match)
    const int arow = tid >> 3;                   // 0..63
    const int axs = ((tid & 7) ^ ((arow & 3) << 1)) * 8;
    const u16* Asrc = A  + (size_t)(m0 + arow) * KDIM + axs;
    const u16* Bsrc = BT + (size_t)(n0 + arow) * KDIM + axs;
    u16* Adst = lds + tid * 8;
    u16* Bdst = lds + 32768 + tid * 8;

    f32x4 acc[8][4];
#pragma unroll
    for (int i = 0; i < 8; ++i)
#pragma unroll
        for (int j = 0; j < 4; ++j) acc[i][j] = {0.f, 0.f, 0.f, 0.f};
    bf16x8 af[4][2][2];   // [quad][mf-within][kk]
    bf16x8 bfr[4][2];     // [nf][kk]

    // ---- prologue: stage K0 fully + K1 {A0,B0,B1}; A1(K1) staged at iter0 ph1
    STAGE_A(0, 0); STAGE_A(0, 1); STAGE_B(0, 0); STAGE_B(0, 1);
    VM4();
    STAGE_A(1, 0); STAGE_B(1, 0); STAGE_B(1, 1);
    VM6();
    BAR();

    // ---- steady iterations: compute K(2i) [buf0] ph1-4, K(2i+1) [buf1] ph5-8
#pragma unroll 1
    for (int i = 0; i < 3; ++i) {
        // ph1: read B(buf0)+Aq0(buf0); stage A1(2i+1)
        LDB(0); LDAQ(0, 0); STAGE_A(2*i + 1, 1);
        BAR(); LGKM0(); MFMAQ(0); BAR();
        // ph2: read Aq1,Aq2(buf0); stage B0(2i+2)
        LDAQ(1, 0); LDAQ(2, 0); STAGE_B(2*i + 2, 0);
        BAR(); LGKM0(); MFMAQ(1); BAR();
        // ph3: read Aq3(buf0); stage B1(2i+2)
        LDAQ(3, 0); STAGE_B(2*i + 2, 1);
        BAR(); LGKM0(); MFMAQ(2); BAR();
        // ph4: stage A0(2i+2); counted vmcnt publishes stages <= ph1
        STAGE_A(2*i + 2, 0);
        BAR(); LGKM0(); MFMAQ(3); VM6(); BAR();
        // ph5: read B(buf1)+Aq0(buf1); stage A1(2i+2)
        LDB(1); LDAQ(0, 1); STAGE_A(2*i + 2, 1);
        BAR(); LGKM0(); MFMAQ(0); BAR();
        // ph6: read Aq1,Aq2(buf1); stage B0(2i+3)
        LDAQ(1, 1); LDAQ(2, 1); STAGE_B(2*i + 3, 0);
        BAR(); LGKM0(); MFMAQ(1); BAR();
        // ph7: read Aq3(buf1); stage B1(2i+3)
        LDAQ(3, 1); STAGE_B(2*i + 3, 1);
        BAR(); LGKM0(); MFMAQ(2); BAR();
        // ph8: stage A0(2i+3); counted vmcnt publishes stages <= ph5
        STAGE_A(2*i + 3, 0);
        BAR(); LGKM0(); MFMAQ(3); VM6(); BAR();
    }
    // ---- final iteration: K6 (buf0), K7 (buf1); only A1(K7) left to stage
    LDB(0); LDAQ(0, 0); STAGE_A(7, 1);
    BAR(); LGKM0(); MFMAQ(0); BAR();
    LDAQ(1, 0); LDAQ(2, 0);
    BAR(); LGKM0(); MFMAQ(1); BAR();
    LDAQ(3, 0);
    BAR(); LGKM0(); MFMAQ(2); BAR();
    BAR(); LGKM0(); MFMAQ(3); VM0(); BAR();
    LDB(1); LDAQ(0, 1);
    BAR(); LGKM0(); MFMAQ(0); BAR();
    LDAQ(1, 1); LDAQ(2, 1);
    BAR(); LGKM0(); MFMAQ(1); BAR();
    LDAQ(3, 1);
    BAR(); LGKM0(); MFMAQ(2); BAR();
    BAR(); LGKM0(); MFMAQ(3);

    if (EPI == 0) {
#pragma unroll
        for (int mf = 0; mf < 8; ++mf) {
#pragma unroll
            for (int nf = 0; nf < 4; ++nf) {
                int col = n0 + wc * 64 + nf * 16 + lr;
                int row = m0 + wr * 128 + mf * 16 + lg * 4;
#pragma unroll
                for (int rr = 0; rr < 4; ++rr)
                    outB[(size_t)(row + rr) * NT + col] = f2bf(acc[mf][nf][rr]);
            }
        }
    } else {
        // un-window via LDS transpose: tile = 4 windows (b,wh fixed), 8h x 32w, 256 c
        int win0 = m0 >> 6;
        int b_img = win0 >> 8, wl = win0 & 255;
        int h0 = (wl >> 4) * 8, w0 = (wl & 15) * 8;
        float* fbuf = reinterpret_cast<float*>(lds);
        __syncthreads();
#pragma unroll
        for (int s = 0; s < 2; ++s) {
            if ((wc >> 1) == s) {
                int half = wc & 1;
                float* cb = fbuf + half * 16384;   // [64 c'][8 h][8 slot] f32x4-slots
#pragma unroll
                for (int mf = 0; mf < 8; ++mf) {
#pragma unroll
                    for (int nf = 0; nf < 4; ++nf) {
                        int cp = nf * 16 + lr;
                        int row = wr * 128 + mf * 16 + lg * 4;
                        int h = (row >> 3) & 7;
                        int sl = ((row >> 6) & 3) * 2 + ((row >> 2) & 1);
                        float bb = bias[n0 + (2 * s + half) * 64 + cp];
                        f32x4 v = acc[mf][nf];
                        float4 o = {v[0] + bb, v[1] + bb, v[2] + bb, v[3] + bb};
                        *reinterpret_cast<float4*>(&cb[cp * 256 + h * 32 + (sl ^ (cp & 7)) * 4]) = o;
                    }
                }
            }
            __syncthreads();
#pragma unroll
            for (int j = 0; j < 16; ++j) {
                int flat = j * 512 + tid;
                int half = flat >> 12, f = flat & 4095;
                int cp = f >> 6, h = (f >> 3) & 7, sl = f & 7;
                int col = n0 + (2 * s + half) * 64 + cp;
                float4 v = *reinterpret_cast<const float4*>(
                    &fbuf[half * 16384 + cp * 256 + h * 32 + ((sl ^ (cp & 7))) * 4]);
                *reinterpret_cast<float4*>(outF + (size_t)(b_img * C_DIM + col) * HW
                                           + (size_t)(h0 + h) * W_IMG + w0 + sl * 4) = v;
            }
            __syncthreads();
        }
    }
}

// ---------------- attention: one wave per (window, head) ----------------
__global__ __launch_bounds__(64) void sa_attn_kernel(const u16* __restrict__ qkv,
        const float* __restrict__ biasP, u16* __restrict__ attnc) {
    __shared__ u16 VT[32 * 80];
    __shared__ u16 Ps[64 * 80];
    int win = blockIdx.x >> 4, head = blockIdx.x & 15;
    int lane = threadIdx.x, lr = lane & 15, lg = lane >> 4;
    const u16* base = qkv + (size_t)win * 64 * QKV_N + head * HD;

#pragma unroll
    for (int p = 0; p < 4; ++p) {
        int idx = p * 64 + lane;
        int row = idx >> 2, seg = idx & 3;
        union { uint4 u; u16 s[8]; } cv;
        cv.u = *reinterpret_cast<const uint4*>(base + (size_t)row * QKV_N + 1024 + seg * 8);
#pragma unroll
        for (int e = 0; e < 8; ++e) VT[(seg * 8 + e) * 80 + row] = cv.s[e];
    }

    bf16x8 qa[4], kb[4];
#pragma unroll
    for (int mt = 0; mt < 4; ++mt)
        qa[mt] = *reinterpret_cast<const bf16x8*>(base + (size_t)(mt * 16 + lr) * QKV_N + lg * 8);
#pragma unroll
    for (int nt = 0; nt < 4; ++nt)
        kb[nt] = *reinterpret_cast<const bf16x8*>(base + (size_t)(nt * 16 + lr) * QKV_N + 512 + lg * 8);

    f32x4 sacc[4][4];
#pragma unroll
    for (int i = 0; i < 4; ++i)
#pragma unroll
        for (int j = 0; j < 4; ++j) sacc[i][j] = {0.f, 0.f, 0.f, 0.f};
#pragma unroll
    for (int mt = 0; mt < 4; ++mt)
#pragma unroll
        for (int nt = 0; nt < 4; ++nt)
            sacc[mt][nt] = __builtin_amdgcn_mfma_f32_16x16x32_bf16(qa[mt], kb[nt], sacc[mt][nt], 0, 0, 0);

    __syncthreads();

    const float scale = 0.17677669529663687f;
    const float* bp = biasP + head * 64 * 64;
#pragma unroll
    for (int mt = 0; mt < 4; ++mt) {
#pragma unroll
        for (int rr = 0; rr < 4; ++rr) {
            int row = mt * 16 + lg * 4 + rr;
            float vals[4];
#pragma unroll
            for (int nt = 0; nt < 4; ++nt)
                vals[nt] = sacc[mt][nt][rr] * scale + bp[row * 64 + nt * 16 + lr];
            float mx = fmaxf(fmaxf(vals[0], vals[1]), fmaxf(vals[2], vals[3]));
#pragma unroll
            for (int d = 1; d < 16; d <<= 1) mx = fmaxf(mx, __shfl_xor(mx, d, 64));
            float sm = 0.f;
#pragma unroll
            for (int nt = 0; nt < 4; ++nt) { vals[nt] = __expf(vals[nt] - mx); sm += vals[nt]; }
#pragma unroll
            for (int d = 1; d < 16; d <<= 1) sm += __shfl_xor(sm, d, 64);
            float inv = 1.f / sm;
#pragma unroll
            for (int nt = 0; nt < 4; ++nt)
                Ps[row * 80 + nt * 16 + lr] = f2bf(vals[nt] * inv);
        }
    }
    __syncthreads();

    f32x4 oacc[4][2];
#pragma unroll
    for (int i = 0; i < 4; ++i) { oacc[i][0] = {0.f,0.f,0.f,0.f}; oacc[i][1] = {0.f,0.f,0.f,0.f}; }
#pragma unroll
    for (int ks = 0; ks < 2; ++ks) {
        bf16x8 pa[4], vb[2];
#pragma unroll
        for (int mt = 0; mt < 4; ++mt)
            pa[mt] = *reinterpret_cast<const bf16x8*>(&Ps[(mt * 16 + lr) * 80 + ks * 32 + lg * 8]);
#pragma unroll
        for (int n2 = 0; n2 < 2; ++n2)
            vb[n2] = *reinterpret_cast<const bf16x8*>(&VT[(n2 * 16 + lr) * 80 + ks * 32 + lg * 8]);
#pragma unroll
        for (int mt = 0; mt < 4; ++mt)
#pragma unroll
            for (int n2 = 0; n2 < 2; ++n2)
                oacc[mt][n2] = __builtin_amdgcn_mfma_f32_16x16x32_bf16(pa[mt], vb[n2], oacc[mt][n2], 0, 0, 0);
    }

#pragma unroll
    for (int mt = 0; mt < 4; ++mt)
#pragma unroll
        for (int n2 = 0; n2 < 2; ++n2)
#pragma unroll
            for (int rr = 0; rr < 4; ++rr) {
                int row = mt * 16 + lg * 4 + rr;
                attnc[(size_t)(win * 64 + row) * C_DIM + head * HD + n2 * 16 + lr] =
                    f2bf(oacc[mt][n2][rr]);
            }
}

// ---------------- host ----------------
extern "C" void kernel_launch(void* const* d_in, const int* in_sizes, int n_in,
                              void* d_out, int out_size, void* d_ws, size_t ws_size,
                              hipStream_t stream) {
    const float* x          = (const float*)d_in[0];
    const float* gamma      = (const float*)d_in[1];
    const float* beta       = (const float*)d_in[2];
    const float* w_qkv      = (const float*)d_in[3];
    const float* w_proj     = (const float*)d_in[4];
    const float* b_proj     = (const float*)d_in[5];
    const float* bias_table = (const float*)d_in[6];
    float* out = (float*)d_out;

    char* ws = (char*)d_ws;
    size_t off = 0;
    auto alloc = [&](size_t bytes) {
        char* p = ws + off;
        off += (bytes + 255) & ~(size_t)255;
        return p;
    };
    u16*   wqT   = (u16*)alloc((size_t)KDIM * QKV_N * 2);
    u16*   wpT   = (u16*)alloc((size_t)KDIM * C_DIM * 2);
    float* biasP = (float*)alloc((size_t)NHEAD * 64 * 64 * 4);
    float* mu    = (float*)alloc((size_t)NTOK * 4);
    float* rsig  = (float*)alloc((size_t)NTOK * 4);
    u16*   xnc   = (u16*)alloc((size_t)NTOK * C_DIM * 2);
    u16*   qkvc  = (u16*)alloc((size_t)NTOK * QKV_N * 2);
    u16*   attnc = (u16*)alloc((size_t)NTOK * C_DIM * 2);

    sa_prep_kernel<<<4352, 256, 0, stream>>>(w_qkv, w_proj, bias_table, wqT, wpT, biasP);
    sa_ln_stats_kernel<<<256, 256, 0, stream>>>(x, mu, rsig);
    sa_ln_norm_kernel<<<4096, 256, 0, stream>>>(x, gamma, beta, mu, rsig, xnc);
    sa_gemm8_kernel<0><<<256 * 6, 512, 0, stream>>>(xnc, wqT, qkvc, nullptr, nullptr, 6, QKV_N);
    sa_attn_kernel<<<NWIN * NHEAD, 64, 0, stream>>>(qkvc, biasP, attnc);
    sa_gemm8_kernel<1><<<256 * 2, 512, 0, stream>>>(attnc, wpT, nullptr, out, b_proj, 2, C_DIM);
}